// Round 1
// baseline (487.903 us; speedup 1.0000x reference)
//
#include <hip/hip_runtime.h>
#include <hip/hip_bf16.h>
#include <stdint.h>

#define NN 50000
#define EE 500000

typedef __attribute__((ext_vector_type(8))) short short8;
typedef __attribute__((ext_vector_type(4))) float f32x4;
typedef __attribute__((ext_vector_type(4))) unsigned short u16x4;

__device__ __forceinline__ unsigned short f2bf(float f) {
  union { float f; uint32_t u; } v; v.f = f;
  uint32_t u = v.u;
  return (unsigned short)((u + 0x7FFFu + ((u >> 16) & 1u)) >> 16);
}

// ---- x (f32) -> bf16, 4 elems per thread
__global__ void k_cvt(const float* __restrict__ x, unsigned short* __restrict__ xb, int n4) {
  int i = blockIdx.x * blockDim.x + threadIdx.x;
  if (i >= n4) return;
  const float4 v = reinterpret_cast<const float4*>(x)[i];
  u16x4 o;
  o[0] = f2bf(v.x); o[1] = f2bf(v.y); o[2] = f2bf(v.z); o[3] = f2bf(v.w);
  reinterpret_cast<u16x4*>(xb)[i] = o;
}

// ---- W [256][512] f32 -> Wt [512][256] bf16 : rows 0..255 = W1-W2, rows 256..511 = W2
__global__ void k_prep(const float* __restrict__ W, unsigned short* __restrict__ wt) {
  int i = blockIdx.x * blockDim.x + threadIdx.x;
  if (i >= 512 * 256) return;
  int o = i >> 8, k = i & 255;
  float v = (o < 256) ? (W[o * 512 + k] - W[o * 512 + 256 + k])
                      : W[(o - 256) * 512 + 256 + k];
  wt[i] = f2bf(v);
}

// ---- Y[M][512] = xb[M][256] @ wt[512][256]^T  (+bias on cols<256)
// BM=128 BN=64 BK=32, 4 waves (2x2), each wave 64x32 = 4x2 frags of 16x16x32
__launch_bounds__(256)
__global__ void k_gemm(const unsigned short* __restrict__ xb, const unsigned short* __restrict__ wt,
                       const float* __restrict__ bias, float* __restrict__ Y, int M) {
  __shared__ unsigned short lA[2][128 * 32];
  __shared__ unsigned short lB[2][64 * 32];
  const int tid  = threadIdx.x;
  const int lane = tid & 63, wid = tid >> 6;
  const int wr = wid >> 1, wc = wid & 1;
  const int row0 = blockIdx.x * 128;
  const int col0 = blockIdx.y * 64;

  const int srow = tid >> 2;            // staging row 0..63
  const int schk = tid & 3;             // staging 16B chunk 0..3
  const int ga_r0 = min(row0 + srow, M - 1);
  const int ga_r1 = min(row0 + 64 + srow, M - 1);
  const int gb_r  = col0 + srow;

  const int fl = lane & 15, fh = lane >> 4;

  // swizzled LDS element offset for (row, chunk)
  #define SWZ(row, c) ((row) * 32 + (((c) ^ (((row) >> 1) & 3)) * 8))
  const int wA0 = SWZ(srow, schk);
  const int wA1 = SWZ(srow + 64, schk);
  const int wB  = SWZ(srow, schk);

  short8 ra0, ra1, rb;
  f32x4 acc[4][2];
  #pragma unroll
  for (int i = 0; i < 4; ++i)
    #pragma unroll
    for (int j = 0; j < 2; ++j) acc[i][j] = (f32x4){0.f, 0.f, 0.f, 0.f};

  const int koff = schk * 8;
  #define LOADG(kt) { int k0 = (kt) * 32; \
    ra0 = *(const short8*)(xb + (size_t)ga_r0 * 256 + k0 + koff); \
    ra1 = *(const short8*)(xb + (size_t)ga_r1 * 256 + k0 + koff); \
    rb  = *(const short8*)(wt + (size_t)gb_r  * 256 + k0 + koff); }
  #define WRITES(b) { \
    *(short8*)(&lA[b][wA0]) = ra0; \
    *(short8*)(&lA[b][wA1]) = ra1; \
    *(short8*)(&lB[b][wB])  = rb; }

  LOADG(0);
  WRITES(0);
  for (int kt = 0; kt < 8; ++kt) {
    __syncthreads();
    const int cur = kt & 1;
    if (kt < 7) LOADG(kt + 1);
    short8 af[4], bfr[2];
    #pragma unroll
    for (int fm = 0; fm < 4; ++fm)
      af[fm] = *(const short8*)(&lA[cur][SWZ(wr * 64 + fm * 16 + fl, fh)]);
    #pragma unroll
    for (int fn = 0; fn < 2; ++fn)
      bfr[fn] = *(const short8*)(&lB[cur][SWZ(wc * 32 + fn * 16 + fl, fh)]);
    #pragma unroll
    for (int fm = 0; fm < 4; ++fm)
      #pragma unroll
      for (int fn = 0; fn < 2; ++fn)
        acc[fm][fn] = __builtin_amdgcn_mfma_f32_16x16x32_bf16(af[fm], bfr[fn], acc[fm][fn], 0, 0, 0);
    if (kt < 7) WRITES(cur ^ 1);
  }

  #pragma unroll
  for (int fm = 0; fm < 4; ++fm) {
    const int grow_base = row0 + wr * 64 + fm * 16 + fh * 4;
    #pragma unroll
    for (int fn = 0; fn < 2; ++fn) {
      const int gcol = col0 + wc * 32 + fn * 16 + fl;
      const float bv = (gcol < 256) ? bias[gcol] : 0.0f;
      #pragma unroll
      for (int r = 0; r < 4; ++r) {
        const int grow = grow_base + r;
        if (grow < M) Y[(size_t)grow * 512 + gcol] = acc[fm][fn][r] + bv;
      }
    }
  }
  #undef SWZ
  #undef LOADG
  #undef WRITES
}

// ---- CSR build
__global__ void k_hist(const int* __restrict__ dst, int* __restrict__ cnt, int n) {
  int i = blockIdx.x * blockDim.x + threadIdx.x;
  if (i < n) atomicAdd(&cnt[dst[i]], 1);
}

__global__ void k_scan(const int* __restrict__ cnt, int* __restrict__ offs,
                       int* __restrict__ curs, int n) {
  __shared__ int s_wsum[16];
  __shared__ int s_wpre[16];
  __shared__ int s_tot;
  const int tid = threadIdx.x;
  const int lane = tid & 63, wv = tid >> 6;
  int carry = 0;
  for (int base = 0; base < n; base += 1024) {
    const int i = base + tid;
    const int v = (i < n) ? cnt[i] : 0;
    int inc = v;
    #pragma unroll
    for (int d = 1; d < 64; d <<= 1) {
      int t = __shfl_up(inc, d, 64);
      if (lane >= d) inc += t;
    }
    if (lane == 63) s_wsum[wv] = inc;
    __syncthreads();
    if (tid == 0) {
      int s = 0;
      #pragma unroll
      for (int w2 = 0; w2 < 16; ++w2) { int t = s_wsum[w2]; s_wpre[w2] = s; s += t; }
      s_tot = s;
    }
    __syncthreads();
    const int excl = carry + s_wpre[wv] + inc - v;
    if (i < n) { offs[i] = excl; curs[i] = excl; }
    carry += s_tot;
    __syncthreads();
  }
  if (tid == 0) offs[n] = carry;
}

__global__ void k_scatter(const int* __restrict__ src, const int* __restrict__ dst,
                          int* __restrict__ curs, int* __restrict__ ssrc, int n) {
  int i = blockIdx.x * blockDim.x + threadIdx.x;
  if (i < n) {
    int pos = atomicAdd(&curs[dst[i]], 1);
    ssrc[pos] = src[i];
  }
}

// ---- aggregate: one wave per dst node. AGGR=0: out = max (init 0). AGGR=1: out += sum.
template <int AGGR>
__global__ void k_agg(const float* __restrict__ Y, const int* __restrict__ offs,
                      const int* __restrict__ ssrc, float* __restrict__ out) {
  const int node = blockIdx.x * 4 + (threadIdx.x >> 6);
  if (node >= NN) return;
  const int lane = threadIdx.x & 63;
  const int beg = offs[node], end = offs[node + 1];
  if (AGGR == 1 && beg == end) return;

  const f32x4 a4 = *(const f32x4*)(Y + (size_t)node * 512 + (lane << 2));
  f32x4 acc = (f32x4){0.f, 0.f, 0.f, 0.f};

  int e = beg;
  int s_nxt = (e < end) ? ssrc[e] : 0;
  for (; e < end; ++e) {
    const int s = s_nxt;
    if (e + 1 < end) s_nxt = ssrc[e + 1];
    const f32x4 b4 = *(const f32x4*)(Y + (size_t)s * 512 + 256 + (lane << 2));
    #pragma unroll
    for (int j = 0; j < 4; ++j) {
      float m = fmaxf(a4[j] + b4[j], 0.0f);
      if (AGGR == 0) acc[j] = fmaxf(acc[j], m);
      else           acc[j] += m;
    }
  }

  float* op = out + (size_t)node * 256 + (lane << 2);
  if (AGGR == 0) {
    *(f32x4*)op = acc;
  } else {
    f32x4 prev = *(const f32x4*)op;
    #pragma unroll
    for (int j = 0; j < 4; ++j) prev[j] += acc[j];
    *(f32x4*)op = prev;
  }
}

extern "C" void kernel_launch(void* const* d_in, const int* in_sizes, int n_in,
                              void* d_out, int out_size, void* d_ws, size_t ws_size,
                              hipStream_t stream) {
  const float* x     = (const float*)d_in[0];
  const int*   e_tp  = (const int*)d_in[1];
  const int*   e_int = (const int*)d_in[2];
  const float* W_tp  = (const float*)d_in[3];
  const float* b_tp  = (const float*)d_in[4];
  const float* W_int = (const float*)d_in[5];
  const float* b_int = (const float*)d_in[6];
  float* out = (float*)d_out;

  char* w = (char*)d_ws;
  unsigned short* xb = (unsigned short*)w;                      // 25,600,000 B
  unsigned short* wt = (unsigned short*)(w + 25600000);         //    262,144 B
  float* Y   = (float*)(w + 25862144);                          // 102,400,000 B
  int*   cnt = (int*)(w + 128262144);                           //    200,000 B
  int*   offs= (int*)(w + 128462144);                           //    200,016 B
  int*   curs= (int*)(w + 128662160);                           //    200,000 B
  int*   ssrc= (int*)(w + 128862160);                           //  2,000,000 B

  k_cvt<<<dim3(12500), dim3(256), 0, stream>>>(x, xb, 3200000);

  // ---- intersects: max aggregation (writes all of d_out)
  k_prep<<<512, 256, 0, stream>>>(W_int, wt);
  k_gemm<<<dim3(391, 8), dim3(256), 0, stream>>>(xb, wt, b_int, Y, NN);
  hipMemsetAsync(cnt, 0, NN * sizeof(int), stream);
  k_hist<<<1954, 256, 0, stream>>>(e_int + EE, cnt, EE);
  k_scan<<<1, 1024, 0, stream>>>(cnt, offs, curs, NN);
  k_scatter<<<1954, 256, 0, stream>>>(e_int, e_int + EE, curs, ssrc, EE);
  k_agg<0><<<12500, 256, 0, stream>>>(Y, offs, ssrc, out);

  // ---- temp_previous: sum aggregation (accumulates into d_out)
  k_prep<<<512, 256, 0, stream>>>(W_tp, wt);
  k_gemm<<<dim3(391, 8), dim3(256), 0, stream>>>(xb, wt, b_tp, Y, NN);
  hipMemsetAsync(cnt, 0, NN * sizeof(int), stream);
  k_hist<<<1954, 256, 0, stream>>>(e_tp + EE, cnt, EE);
  k_scan<<<1, 1024, 0, stream>>>(cnt, offs, curs, NN);
  k_scatter<<<1954, 256, 0, stream>>>(e_tp, e_tp + EE, curs, ssrc, EE);
  k_agg<1><<<12500, 256, 0, stream>>>(Y, offs, ssrc, out);
}

// Round 2
// 342.495 us; speedup vs baseline: 1.4246x; 1.4246x over previous
//
#include <hip/hip_runtime.h>
#include <hip/hip_bf16.h>
#include <stdint.h>

#define NN 50000
#define EE 500000

typedef __attribute__((ext_vector_type(8))) short short8;
typedef __attribute__((ext_vector_type(4))) float f32x4;
typedef __attribute__((ext_vector_type(4))) unsigned short u16x4;

__device__ __forceinline__ unsigned short f2bf(float f) {
  union { float f; uint32_t u; } v; v.f = f;
  uint32_t u = v.u;
  return (unsigned short)((u + 0x7FFFu + ((u >> 16) & 1u)) >> 16);
}

__device__ __forceinline__ f32x4 bf4(const unsigned short* p) {
  u16x4 v = *(const u16x4*)p;
  f32x4 r;
  #pragma unroll
  for (int j = 0; j < 4; ++j) {
    union { uint32_t u; float f; } c; c.u = ((uint32_t)(unsigned short)v[j]) << 16; r[j] = c.f;
  }
  return r;
}

// ---- x (f32) -> bf16, 4 elems per thread
__global__ void k_cvt(const float* __restrict__ x, unsigned short* __restrict__ xb, int n4) {
  int i = blockIdx.x * blockDim.x + threadIdx.x;
  if (i >= n4) return;
  const float4 v = reinterpret_cast<const float4*>(x)[i];
  u16x4 o;
  o[0] = f2bf(v.x); o[1] = f2bf(v.y); o[2] = f2bf(v.z); o[3] = f2bf(v.w);
  reinterpret_cast<u16x4*>(xb)[i] = o;
}

// ---- combined Wt [1024][256] bf16:
// rows   0..255  : W_int[:, :256] - W_int[:, 256:]   (A_int)
// rows 256..511  : W_int[:, 256:]                    (B_int)
// rows 512..767  : W_tp [:, :256] - W_tp [:, 256:]   (A_tp)
// rows 768..1023 : W_tp [:, 256:]                    (B_tp)
__global__ void k_prep(const float* __restrict__ Wi, const float* __restrict__ Wt,
                       unsigned short* __restrict__ wt) {
  int i = blockIdx.x * blockDim.x + threadIdx.x;
  if (i >= 1024 * 256) return;
  int o = i >> 8, k = i & 255;
  const float* W = (o < 512) ? Wi : Wt;
  int oo = o & 511;
  float v = (oo < 256) ? (W[oo * 512 + k] - W[oo * 512 + 256 + k])
                       : W[(oo - 256) * 512 + 256 + k];
  wt[i] = f2bf(v);
}

// ---- Y[M][1024] (bf16) = xb[M][256] @ wt[1024][256]^T  (+bias on A columns)
// BM=128 BN=64 BK=32, 4 waves (2x2), each wave 64x32 = 4x2 frags of 16x16x32
__launch_bounds__(256)
__global__ void k_gemm(const unsigned short* __restrict__ xb, const unsigned short* __restrict__ wt,
                       const float* __restrict__ b_int, const float* __restrict__ b_tp,
                       unsigned short* __restrict__ Y, int M) {
  __shared__ unsigned short lA[2][128 * 32];
  __shared__ unsigned short lB[2][64 * 32];
  const int tid  = threadIdx.x;
  const int lane = tid & 63, wid = tid >> 6;
  const int wr = wid >> 1, wc = wid & 1;
  const int row0 = blockIdx.x * 128;
  const int col0 = blockIdx.y * 64;

  const int srow = tid >> 2;            // staging row 0..63
  const int schk = tid & 3;             // staging 16B chunk 0..3
  const int ga_r0 = min(row0 + srow, M - 1);
  const int ga_r1 = min(row0 + 64 + srow, M - 1);
  const int gb_r  = col0 + srow;

  const int fl = lane & 15, fh = lane >> 4;

  #define SWZ(row, c) ((row) * 32 + (((c) ^ (((row) >> 1) & 3)) * 8))
  const int wA0 = SWZ(srow, schk);
  const int wA1 = SWZ(srow + 64, schk);
  const int wB  = SWZ(srow, schk);

  short8 ra0, ra1, rb;
  f32x4 acc[4][2];
  #pragma unroll
  for (int i = 0; i < 4; ++i)
    #pragma unroll
    for (int j = 0; j < 2; ++j) acc[i][j] = (f32x4){0.f, 0.f, 0.f, 0.f};

  const int koff = schk * 8;
  #define LOADG(kt) { int k0 = (kt) * 32; \
    ra0 = *(const short8*)(xb + (size_t)ga_r0 * 256 + k0 + koff); \
    ra1 = *(const short8*)(xb + (size_t)ga_r1 * 256 + k0 + koff); \
    rb  = *(const short8*)(wt + (size_t)gb_r  * 256 + k0 + koff); }
  #define WRITES(b) { \
    *(short8*)(&lA[b][wA0]) = ra0; \
    *(short8*)(&lA[b][wA1]) = ra1; \
    *(short8*)(&lB[b][wB])  = rb; }

  LOADG(0);
  WRITES(0);
  for (int kt = 0; kt < 8; ++kt) {
    __syncthreads();
    const int cur = kt & 1;
    if (kt < 7) LOADG(kt + 1);
    short8 af[4], bfr[2];
    #pragma unroll
    for (int fm = 0; fm < 4; ++fm)
      af[fm] = *(const short8*)(&lA[cur][SWZ(wr * 64 + fm * 16 + fl, fh)]);
    #pragma unroll
    for (int fn = 0; fn < 2; ++fn)
      bfr[fn] = *(const short8*)(&lB[cur][SWZ(wc * 32 + fn * 16 + fl, fh)]);
    #pragma unroll
    for (int fm = 0; fm < 4; ++fm)
      #pragma unroll
      for (int fn = 0; fn < 2; ++fn)
        acc[fm][fn] = __builtin_amdgcn_mfma_f32_16x16x32_bf16(af[fm], bfr[fn], acc[fm][fn], 0, 0, 0);
    if (kt < 7) WRITES(cur ^ 1);
  }

  #pragma unroll
  for (int fm = 0; fm < 4; ++fm) {
    const int grow_base = row0 + wr * 64 + fm * 16 + fh * 4;
    #pragma unroll
    for (int fn = 0; fn < 2; ++fn) {
      const int gcol = col0 + wc * 32 + fn * 16 + fl;
      float bv = 0.0f;
      if (gcol < 256) bv = b_int[gcol];
      else if (gcol >= 512 && gcol < 768) bv = b_tp[gcol - 512];
      #pragma unroll
      for (int r = 0; r < 4; ++r) {
        const int grow = grow_base + r;
        if (grow < M) Y[(size_t)grow * 1024 + gcol] = f2bf(acc[fm][fn][r] + bv);
      }
    }
  }
  #undef SWZ
  #undef LOADG
  #undef WRITES
}

// ---- CSR build (both edge types in one launch)
#define HBLK 1954
__global__ void k_hist(const int* __restrict__ di, const int* __restrict__ dt,
                       int* __restrict__ ci, int* __restrict__ ct) {
  int b = blockIdx.x;
  const int* d; int* c;
  if (b < HBLK) { d = di; c = ci; } else { d = dt; c = ct; b -= HBLK; }
  int i = b * 256 + threadIdx.x;
  if (i < EE) atomicAdd(&c[d[i]], 1);
}

// one block per edge type; curs aliases cnt (in-place)
__global__ void k_scan(int* __restrict__ cnt_i, int* __restrict__ offs_i,
                       int* __restrict__ cnt_t, int* __restrict__ offs_t, int n) {
  int* cnt  = blockIdx.x ? cnt_t  : cnt_i;
  int* offs = blockIdx.x ? offs_t : offs_i;
  __shared__ int s_wsum[16];
  __shared__ int s_wpre[16];
  __shared__ int s_tot;
  const int tid = threadIdx.x;
  const int lane = tid & 63, wv = tid >> 6;
  int carry = 0;
  for (int base = 0; base < n; base += 1024) {
    const int i = base + tid;
    const int v = (i < n) ? cnt[i] : 0;
    int inc = v;
    #pragma unroll
    for (int d = 1; d < 64; d <<= 1) {
      int t = __shfl_up(inc, d, 64);
      if (lane >= d) inc += t;
    }
    if (lane == 63) s_wsum[wv] = inc;
    __syncthreads();
    if (tid == 0) {
      int s = 0;
      #pragma unroll
      for (int w2 = 0; w2 < 16; ++w2) { int t = s_wsum[w2]; s_wpre[w2] = s; s += t; }
      s_tot = s;
    }
    __syncthreads();
    const int excl = carry + s_wpre[wv] + inc - v;
    if (i < n) { offs[i] = excl; cnt[i] = excl; }   // cnt becomes cursor
    carry += s_tot;
    __syncthreads();
  }
  if (tid == 0) offs[n] = carry;
}

__global__ void k_scatter(const int* __restrict__ ei, const int* __restrict__ et,
                          int* __restrict__ cur_i, int* __restrict__ cur_t,
                          int* __restrict__ so_i, int* __restrict__ so_t) {
  int b = blockIdx.x;
  const int* e; int* cur; int* so;
  if (b < HBLK) { e = ei; cur = cur_i; so = so_i; } else { e = et; cur = cur_t; so = so_t; b -= HBLK; }
  int i = b * 256 + threadIdx.x;
  if (i < EE) {
    int pos = atomicAdd(&cur[e[EE + i]], 1);
    so[pos] = e[i];
  }
}

// ---- fused aggregate: one wave per dst node; max(int) + sum(tp); single out write
__global__ void k_agg2(const unsigned short* __restrict__ Y,
                       const int* __restrict__ offs_i, const int* __restrict__ src_i,
                       const int* __restrict__ offs_t, const int* __restrict__ src_t,
                       float* __restrict__ out) {
  const int node = blockIdx.x * 4 + (threadIdx.x >> 6);
  if (node >= NN) return;
  const int lane = threadIdx.x & 63;
  const int c4 = lane << 2;
  const size_t rb = (size_t)node * 1024;

  const f32x4 ai = bf4(Y + rb + c4);         // A_int
  const f32x4 at = bf4(Y + rb + 512 + c4);   // A_tp
  f32x4 mx = (f32x4){0.f, 0.f, 0.f, 0.f};
  f32x4 sm = (f32x4){0.f, 0.f, 0.f, 0.f};

  // --- intersects: max aggregation over B_int (cols 256..511)
  {
    int e = offs_i[node];
    const int end = offs_i[node + 1];
    for (; e + 2 <= end; e += 2) {
      const int s0 = src_i[e], s1 = src_i[e + 1];
      const f32x4 b0 = bf4(Y + (size_t)s0 * 1024 + 256 + c4);
      const f32x4 b1 = bf4(Y + (size_t)s1 * 1024 + 256 + c4);
      #pragma unroll
      for (int j = 0; j < 4; ++j) {
        mx[j] = fmaxf(mx[j], fmaxf(ai[j] + b0[j], 0.0f));
        mx[j] = fmaxf(mx[j], fmaxf(ai[j] + b1[j], 0.0f));
      }
    }
    if (e < end) {
      const int s0 = src_i[e];
      const f32x4 b0 = bf4(Y + (size_t)s0 * 1024 + 256 + c4);
      #pragma unroll
      for (int j = 0; j < 4; ++j) mx[j] = fmaxf(mx[j], fmaxf(ai[j] + b0[j], 0.0f));
    }
  }

  // --- temp_previous: sum aggregation over B_tp (cols 768..1023)
  {
    int e = offs_t[node];
    const int end = offs_t[node + 1];
    for (; e + 2 <= end; e += 2) {
      const int s0 = src_t[e], s1 = src_t[e + 1];
      const f32x4 b0 = bf4(Y + (size_t)s0 * 1024 + 768 + c4);
      const f32x4 b1 = bf4(Y + (size_t)s1 * 1024 + 768 + c4);
      #pragma unroll
      for (int j = 0; j < 4; ++j)
        sm[j] += fmaxf(at[j] + b0[j], 0.0f) + fmaxf(at[j] + b1[j], 0.0f);
    }
    if (e < end) {
      const int s0 = src_t[e];
      const f32x4 b0 = bf4(Y + (size_t)s0 * 1024 + 768 + c4);
      #pragma unroll
      for (int j = 0; j < 4; ++j) sm[j] += fmaxf(at[j] + b0[j], 0.0f);
    }
  }

  f32x4 o;
  #pragma unroll
  for (int j = 0; j < 4; ++j) o[j] = mx[j] + sm[j];
  *(f32x4*)(out + (size_t)node * 256 + c4) = o;
}

extern "C" void kernel_launch(void* const* d_in, const int* in_sizes, int n_in,
                              void* d_out, int out_size, void* d_ws, size_t ws_size,
                              hipStream_t stream) {
  const float* x     = (const float*)d_in[0];
  const int*   e_tp  = (const int*)d_in[1];
  const int*   e_int = (const int*)d_in[2];
  const float* W_tp  = (const float*)d_in[3];
  const float* b_tp  = (const float*)d_in[4];
  const float* W_int = (const float*)d_in[5];
  const float* b_int = (const float*)d_in[6];
  float* out = (float*)d_out;

  char* w = (char*)d_ws;
  // Y first; xb/wt follow; CSR aliases the xb region (written only after GEMM)
  unsigned short* Y  = (unsigned short*)w;                       // 102,400,000 B
  unsigned short* xb = (unsigned short*)(w + 102400000);         //  25,600,000 B
  unsigned short* wt = (unsigned short*)(w + 128000000);         //     524,288 B -> peak 128.5 MB
  char* w2 = w + 102400000;                                      // CSR region (aliases xb)
  int* cnt_i  = (int*)(w2);                                      // 200,000 (becomes cursor)
  int* cnt_t  = (int*)(w2 + 200000);                             // 200,000
  int* offs_i = (int*)(w2 + 400000);                             // 200,064
  int* offs_t = (int*)(w2 + 600064);                             // 200,064
  int* ssrc_i = (int*)(w2 + 800128);                             // 2,000,000
  int* ssrc_t = (int*)(w2 + 2800128);                            // 2,000,000

  k_cvt<<<dim3(12500), dim3(256), 0, stream>>>(x, xb, 3200000);
  k_prep<<<1024, 256, 0, stream>>>(W_int, W_tp, wt);
  k_gemm<<<dim3(391, 16), dim3(256), 0, stream>>>(xb, wt, b_int, b_tp, Y, NN);

  hipMemsetAsync(cnt_i, 0, 400000, stream);  // both cnt arrays (contiguous)
  k_hist<<<2 * HBLK, 256, 0, stream>>>(e_int + EE, e_tp + EE, cnt_i, cnt_t);
  k_scan<<<2, 1024, 0, stream>>>(cnt_i, offs_i, cnt_t, offs_t, NN);
  k_scatter<<<2 * HBLK, 256, 0, stream>>>(e_int, e_tp, cnt_i, cnt_t, ssrc_i, ssrc_t);

  k_agg2<<<12500, 256, 0, stream>>>(Y, offs_i, ssrc_i, offs_t, ssrc_t, out);
}

// Round 3
// 324.064 us; speedup vs baseline: 1.5056x; 1.0569x over previous
//
#include <hip/hip_runtime.h>
#include <hip/hip_bf16.h>
#include <stdint.h>

#define NN 50000
#define EE 500000

typedef __attribute__((ext_vector_type(8))) short short8;
typedef __attribute__((ext_vector_type(4))) float f32x4;
typedef __attribute__((ext_vector_type(4))) unsigned short u16x4;

__device__ __forceinline__ unsigned short f2bf(float f) {
  union { float f; uint32_t u; } v; v.f = f;
  uint32_t u = v.u;
  return (unsigned short)((u + 0x7FFFu + ((u >> 16) & 1u)) >> 16);
}

__device__ __forceinline__ f32x4 bf4(const unsigned short* p) {
  u16x4 v = *(const u16x4*)p;
  f32x4 r;
  #pragma unroll
  for (int j = 0; j < 4; ++j) {
    union { uint32_t u; float f; } c; c.u = ((uint32_t)(unsigned short)v[j]) << 16; r[j] = c.f;
  }
  return r;
}

// ---- combined Wt [1024][256] bf16:
// rows   0..255  : W_int[:, :256] - W_int[:, 256:]   (A_int)
// rows 256..511  : W_int[:, 256:]                    (B_int)
// rows 512..767  : W_tp [:, :256] - W_tp [:, 256:]   (A_tp)
// rows 768..1023 : W_tp [:, 256:]                    (B_tp)
__global__ void k_prep(const float* __restrict__ Wi, const float* __restrict__ Wt,
                       unsigned short* __restrict__ wt) {
  int i = blockIdx.x * blockDim.x + threadIdx.x;
  if (i >= 1024 * 256) return;
  int o = i >> 8, k = i & 255;
  const float* W = (o < 512) ? Wi : Wt;
  int oo = o & 511;
  float v = (oo < 256) ? (W[oo * 512 + k] - W[oo * 512 + 256 + k])
                       : W[(oo - 256) * 512 + 256 + k];
  wt[i] = f2bf(v);
}

// ---- Y[M][1024] (bf16) = x[M][256](f32, cvt inline) @ wt[1024][256]^T (+bias on A cols)
// BM=128 BN=128 BK=32, 4 waves (2x2), each wave 64x64 = 4x4 frags of 16x16x32
// Epilogue: LDS-staged bf16 tile -> full-line coalesced global stores (no RMW).
__launch_bounds__(256)
__global__ void k_gemm(const float* __restrict__ x, const unsigned short* __restrict__ wt,
                       const float* __restrict__ b_int, const float* __restrict__ b_tp,
                       unsigned short* __restrict__ Y, int M) {
  __shared__ unsigned short sm[2][8192];   // [buf][ A:4096 | B:4096 ]  = 32 KB
  const int tid  = threadIdx.x;
  const int lane = tid & 63, wid = tid >> 6;
  const int wr = wid >> 1, wc = wid & 1;
  const int col0 = blockIdx.x * 128;       // 8 col blocks (x fastest -> A panel L2 reuse)
  const int row0 = blockIdx.y * 128;

  const int srow = tid >> 2;               // staging row 0..63
  const int schk = tid & 3;                // 16B chunk (8 elems)
  const int ga_r0 = min(row0 + srow, M - 1);
  const int ga_r1 = min(row0 + 64 + srow, M - 1);
  const int gb_r0 = col0 + srow;
  const int gb_r1 = col0 + 64 + srow;

  const int fl = lane & 15, fh = lane >> 4;

  #define SWZ(row, c) ((row) * 32 + (((c) ^ (((row) >> 1) & 3)) * 8))
  const int wA0 = SWZ(srow, schk);
  const int wA1 = SWZ(srow + 64, schk);

  f32x4 a0a, a0b, a1a, a1b;
  short8 rb0, rb1;
  f32x4 acc[4][4];
  #pragma unroll
  for (int i = 0; i < 4; ++i)
    #pragma unroll
    for (int j = 0; j < 4; ++j) acc[i][j] = (f32x4){0.f, 0.f, 0.f, 0.f};

  const int koff = schk * 8;
  #define LOADG(kt) { int k0 = (kt) * 32; \
    const float* p0 = x + (size_t)ga_r0 * 256 + k0 + koff; \
    const float* p1 = x + (size_t)ga_r1 * 256 + k0 + koff; \
    a0a = *(const f32x4*)p0; a0b = *(const f32x4*)(p0 + 4); \
    a1a = *(const f32x4*)p1; a1b = *(const f32x4*)(p1 + 4); \
    rb0 = *(const short8*)(wt + (size_t)gb_r0 * 256 + k0 + koff); \
    rb1 = *(const short8*)(wt + (size_t)gb_r1 * 256 + k0 + koff); }
  #define WRITES(b) { \
    short8 ra0, ra1; \
    _Pragma("unroll") \
    for (int j = 0; j < 4; ++j) { \
      ra0[j] = (short)f2bf(a0a[j]); ra0[j + 4] = (short)f2bf(a0b[j]); \
      ra1[j] = (short)f2bf(a1a[j]); ra1[j + 4] = (short)f2bf(a1b[j]); \
    } \
    *(short8*)(&sm[b][wA0]) = ra0; \
    *(short8*)(&sm[b][wA1]) = ra1; \
    *(short8*)(&sm[b][4096 + wA0]) = rb0; \
    *(short8*)(&sm[b][4096 + wA1]) = rb1; }

  LOADG(0);
  WRITES(0);
  for (int kt = 0; kt < 8; ++kt) {
    __syncthreads();
    const int cur = kt & 1;
    if (kt < 7) LOADG(kt + 1);
    const unsigned short* pA = &sm[cur][0];
    const unsigned short* pB = &sm[cur][4096];
    short8 af[4], bfr[4];
    #pragma unroll
    for (int fm = 0; fm < 4; ++fm)
      af[fm] = *(const short8*)(pA + SWZ(wr * 64 + fm * 16 + fl, fh));
    #pragma unroll
    for (int fn = 0; fn < 4; ++fn)
      bfr[fn] = *(const short8*)(pB + SWZ(wc * 64 + fn * 16 + fl, fh));
    #pragma unroll
    for (int fm = 0; fm < 4; ++fm)
      #pragma unroll
      for (int fn = 0; fn < 4; ++fn)
        acc[fm][fn] = __builtin_amdgcn_mfma_f32_16x16x32_bf16(af[fm], bfr[fn], acc[fm][fn], 0, 0, 0);
    if (kt < 7) WRITES(cur ^ 1);
  }
  #undef SWZ
  #undef LOADG
  #undef WRITES

  // ---- epilogue: stage 128x128 bf16 tile in LDS, then full-line stores
  __syncthreads();
  unsigned short* tile = &sm[0][0];        // 16384 elems = 32 KB (both buffers)

  float bv[4];
  #pragma unroll
  for (int fn = 0; fn < 4; ++fn) {
    const int gcol = col0 + wc * 64 + fn * 16 + fl;
    bv[fn] = (gcol < 256) ? b_int[gcol]
           : (gcol >= 512 && gcol < 768) ? b_tp[gcol - 512] : 0.0f;
  }
  #pragma unroll
  for (int fm = 0; fm < 4; ++fm) {
    const int rbase = wr * 64 + fm * 16 + fh * 4;
    #pragma unroll
    for (int fn = 0; fn < 4; ++fn) {
      const int col = wc * 64 + fn * 16 + fl;
      #pragma unroll
      for (int r = 0; r < 4; ++r) {
        const int row = rbase + r;
        tile[(row * 128 + col) ^ ((row & 7) << 3)] = f2bf(acc[fm][fn][r] + bv[fn]);
      }
    }
  }
  __syncthreads();

  const int trow = tid >> 4;               // 16 rows per pass
  const int tchk = tid & 15;               // 16B chunk (8 elems)
  #pragma unroll
  for (int pass = 0; pass < 8; ++pass) {
    const int row = pass * 16 + trow;
    const int grow = row0 + row;
    if (grow < M) {
      const short8 v = *(const short8*)&tile[(row * 128 + tchk * 8) ^ ((row & 7) << 3)];
      *(short8*)&Y[(size_t)grow * 1024 + col0 + tchk * 8] = v;
    }
  }
}

// ---- CSR build (both edge types in one launch)
#define HBLK 1954
__global__ void k_hist(const int* __restrict__ di, const int* __restrict__ dt,
                       int* __restrict__ ci, int* __restrict__ ct) {
  int b = blockIdx.x;
  const int* d; int* c;
  if (b < HBLK) { d = di; c = ci; } else { d = dt; c = ct; b -= HBLK; }
  int i = b * 256 + threadIdx.x;
  if (i < EE) atomicAdd(&c[d[i]], 1);
}

// one block per edge type; cnt becomes cursor (in-place)
__global__ void k_scan(int* __restrict__ cnt_i, int* __restrict__ offs_i,
                       int* __restrict__ cnt_t, int* __restrict__ offs_t, int n) {
  int* cnt  = blockIdx.x ? cnt_t  : cnt_i;
  int* offs = blockIdx.x ? offs_t : offs_i;
  __shared__ int s_wsum[16];
  __shared__ int s_wpre[16];
  __shared__ int s_tot;
  const int tid = threadIdx.x;
  const int lane = tid & 63, wv = tid >> 6;
  int carry = 0;
  for (int base = 0; base < n; base += 1024) {
    const int i = base + tid;
    const int v = (i < n) ? cnt[i] : 0;
    int inc = v;
    #pragma unroll
    for (int d = 1; d < 64; d <<= 1) {
      int t = __shfl_up(inc, d, 64);
      if (lane >= d) inc += t;
    }
    if (lane == 63) s_wsum[wv] = inc;
    __syncthreads();
    if (tid == 0) {
      int s = 0;
      #pragma unroll
      for (int w2 = 0; w2 < 16; ++w2) { int t = s_wsum[w2]; s_wpre[w2] = s; s += t; }
      s_tot = s;
    }
    __syncthreads();
    const int excl = carry + s_wpre[wv] + inc - v;
    if (i < n) { offs[i] = excl; cnt[i] = excl; }
    carry += s_tot;
    __syncthreads();
  }
  if (tid == 0) offs[n] = carry;
}

__global__ void k_scatter(const int* __restrict__ ei, const int* __restrict__ et,
                          int* __restrict__ cur_i, int* __restrict__ cur_t,
                          int* __restrict__ so_i, int* __restrict__ so_t) {
  int b = blockIdx.x;
  const int* e; int* cur; int* so;
  if (b < HBLK) { e = ei; cur = cur_i; so = so_i; } else { e = et; cur = cur_t; so = so_t; b -= HBLK; }
  int i = b * 256 + threadIdx.x;
  if (i < EE) {
    int pos = atomicAdd(&cur[e[EE + i]], 1);
    so[pos] = e[i];
  }
}

// ---- fused aggregate: one wave per dst node; max(int) + sum(tp); single out write
__global__ void k_agg2(const unsigned short* __restrict__ Y,
                       const int* __restrict__ offs_i, const int* __restrict__ src_i,
                       const int* __restrict__ offs_t, const int* __restrict__ src_t,
                       float* __restrict__ out) {
  const int node = blockIdx.x * 4 + (threadIdx.x >> 6);
  if (node >= NN) return;
  const int lane = threadIdx.x & 63;
  const int c4 = lane << 2;
  const size_t rb = (size_t)node * 1024;

  const f32x4 ai = bf4(Y + rb + c4);         // A_int
  const f32x4 at = bf4(Y + rb + 512 + c4);   // A_tp
  f32x4 mx = (f32x4){0.f, 0.f, 0.f, 0.f};
  f32x4 sm = (f32x4){0.f, 0.f, 0.f, 0.f};

  // --- intersects: max over B_int (cols 256..511)
  {
    int e = offs_i[node];
    const int end = offs_i[node + 1];
    for (; e + 4 <= end; e += 4) {
      const int s0 = src_i[e], s1 = src_i[e + 1], s2 = src_i[e + 2], s3 = src_i[e + 3];
      const f32x4 b0 = bf4(Y + (size_t)s0 * 1024 + 256 + c4);
      const f32x4 b1 = bf4(Y + (size_t)s1 * 1024 + 256 + c4);
      const f32x4 b2 = bf4(Y + (size_t)s2 * 1024 + 256 + c4);
      const f32x4 b3 = bf4(Y + (size_t)s3 * 1024 + 256 + c4);
      #pragma unroll
      for (int j = 0; j < 4; ++j) {
        float m0 = fmaxf(fmaxf(ai[j] + b0[j], 0.0f), fmaxf(ai[j] + b1[j], 0.0f));
        float m1 = fmaxf(fmaxf(ai[j] + b2[j], 0.0f), fmaxf(ai[j] + b3[j], 0.0f));
        mx[j] = fmaxf(mx[j], fmaxf(m0, m1));
      }
    }
    for (; e < end; ++e) {
      const int s0 = src_i[e];
      const f32x4 b0 = bf4(Y + (size_t)s0 * 1024 + 256 + c4);
      #pragma unroll
      for (int j = 0; j < 4; ++j) mx[j] = fmaxf(mx[j], fmaxf(ai[j] + b0[j], 0.0f));
    }
  }

  // --- temp_previous: sum over B_tp (cols 768..1023)
  {
    int e = offs_t[node];
    const int end = offs_t[node + 1];
    for (; e + 4 <= end; e += 4) {
      const int s0 = src_t[e], s1 = src_t[e + 1], s2 = src_t[e + 2], s3 = src_t[e + 3];
      const f32x4 b0 = bf4(Y + (size_t)s0 * 1024 + 768 + c4);
      const f32x4 b1 = bf4(Y + (size_t)s1 * 1024 + 768 + c4);
      const f32x4 b2 = bf4(Y + (size_t)s2 * 1024 + 768 + c4);
      const f32x4 b3 = bf4(Y + (size_t)s3 * 1024 + 768 + c4);
      #pragma unroll
      for (int j = 0; j < 4; ++j)
        sm[j] += (fmaxf(at[j] + b0[j], 0.0f) + fmaxf(at[j] + b1[j], 0.0f))
               + (fmaxf(at[j] + b2[j], 0.0f) + fmaxf(at[j] + b3[j], 0.0f));
    }
    for (; e < end; ++e) {
      const int s0 = src_t[e];
      const f32x4 b0 = bf4(Y + (size_t)s0 * 1024 + 768 + c4);
      #pragma unroll
      for (int j = 0; j < 4; ++j) sm[j] += fmaxf(at[j] + b0[j], 0.0f);
    }
  }

  f32x4 o;
  #pragma unroll
  for (int j = 0; j < 4; ++j) o[j] = mx[j] + sm[j];
  *(f32x4*)(out + (size_t)node * 256 + c4) = o;
}

extern "C" void kernel_launch(void* const* d_in, const int* in_sizes, int n_in,
                              void* d_out, int out_size, void* d_ws, size_t ws_size,
                              hipStream_t stream) {
  const float* x     = (const float*)d_in[0];
  const int*   e_tp  = (const int*)d_in[1];
  const int*   e_int = (const int*)d_in[2];
  const float* W_tp  = (const float*)d_in[3];
  const float* b_tp  = (const float*)d_in[4];
  const float* W_int = (const float*)d_in[5];
  const float* b_int = (const float*)d_in[6];
  float* out = (float*)d_out;

  char* w = (char*)d_ws;
  unsigned short* Y  = (unsigned short*)w;          // 102,400,000 B
  char* w2 = w + 102400000;                         // CSR region
  int* cnt_i  = (int*)(w2);                         // 200,000 (becomes cursor)
  int* cnt_t  = (int*)(w2 + 200000);                // 200,000
  int* offs_i = (int*)(w2 + 400000);                // 200,064
  int* offs_t = (int*)(w2 + 600064);                // 200,064
  int* ssrc_i = (int*)(w2 + 800128);                // 2,000,000
  int* ssrc_t = (int*)(w2 + 2800128);               // 2,000,000
  unsigned short* wt = (unsigned short*)(w2 + 4800128); // 524,288  -> peak ~107.7 MB

  k_prep<<<1024, 256, 0, stream>>>(W_int, W_tp, wt);
  k_gemm<<<dim3(8, 391), dim3(256), 0, stream>>>(x, wt, b_int, b_tp, Y, NN);

  hipMemsetAsync(cnt_i, 0, 400000, stream);
  k_hist<<<2 * HBLK, 256, 0, stream>>>(e_int + EE, e_tp + EE, cnt_i, cnt_t);
  k_scan<<<2, 1024, 0, stream>>>(cnt_i, offs_i, cnt_t, offs_t, NN);
  k_scatter<<<2 * HBLK, 256, 0, stream>>>(e_int, e_tp, cnt_i, cnt_t, ssrc_i, ssrc_t);

  k_agg2<<<12500, 256, 0, stream>>>(Y, offs_i, ssrc_i, offs_t, ssrc_t, out);
}

// Round 4
// 290.231 us; speedup vs baseline: 1.6811x; 1.1166x over previous
//
#include <hip/hip_runtime.h>
#include <hip/hip_bf16.h>
#include <stdint.h>

#define NN 50000
#define EE 500000

typedef __attribute__((ext_vector_type(8))) short short8;
typedef __attribute__((ext_vector_type(4))) float f32x4;
typedef __attribute__((ext_vector_type(4))) unsigned short u16x4;

__device__ __forceinline__ unsigned short f2bf(float f) {
  union { float f; uint32_t u; } v; v.f = f;
  uint32_t u = v.u;
  return (unsigned short)((u + 0x7FFFu + ((u >> 16) & 1u)) >> 16);
}

__device__ __forceinline__ f32x4 bf4(const unsigned short* p) {
  u16x4 v = *(const u16x4*)p;
  f32x4 r;
  #pragma unroll
  for (int j = 0; j < 4; ++j) {
    union { uint32_t u; float f; } c; c.u = ((uint32_t)(unsigned short)v[j]) << 16; r[j] = c.f;
  }
  return r;
}

// ---- combined Wt [1024][256] bf16:
// rows   0..255  : W_int[:, :256] - W_int[:, 256:]   (A_int)
// rows 256..511  : W_int[:, 256:]                    (B_int)
// rows 512..767  : W_tp [:, :256] - W_tp [:, 256:]   (A_tp)
// rows 768..1023 : W_tp [:, 256:]                    (B_tp)
__global__ void k_prep(const float* __restrict__ Wi, const float* __restrict__ Wt,
                       unsigned short* __restrict__ wt) {
  int i = blockIdx.x * blockDim.x + threadIdx.x;
  if (i >= 1024 * 256) return;
  int o = i >> 8, k = i & 255;
  const float* W = (o < 512) ? Wi : Wt;
  int oo = o & 511;
  float v = (oo < 256) ? (W[oo * 512 + k] - W[oo * 512 + 256 + k])
                       : W[(oo - 256) * 512 + 256 + k];
  wt[i] = f2bf(v);
}

// LDS swizzles: chunk = 16B (8 bf16) unit; XOR low-3 chunk bits with row to
// spread the 8 16B bank-slots (2-way residual = free per m136).
#define SWZA(row, c) ((row) * 256 + ((((c) ^ ((row) & 7))) << 3))   // A: 32 chunks/row
#define SWZB(row, c) ((row) * 64  + ((((c) ^ ((row) & 7))) << 3))   // B: 8 chunks/row
#define SCR(row, c)  ((row) * 128 + ((((c) ^ ((row) & 7))) << 3))   // epi: 16 chunks/row

// ---- Y[M][1024](bf16) = x[M][256](f32) @ wt[1024][256]^T  (+bias on A cols)
// One block owns a 128-row A panel (whole panel in LDS, read from HBM once)
// and sweeps all 8 col-tiles of 128. BK=64, single B buffer + reg prefetch.
// LDS = 64K (A) + 16K (B/epilogue scratch) = 80 KB -> 2 blocks/CU.
__launch_bounds__(256, 2)
__global__ void k_gemm(const float* __restrict__ x, const unsigned short* __restrict__ wt,
                       const float* __restrict__ b_int, const float* __restrict__ b_tp,
                       unsigned short* __restrict__ Y, int M) {
  __shared__ unsigned short lA[128 * 256];   // 64 KB
  __shared__ unsigned short lB[128 * 64];    // 16 KB (B tile / epilogue scratch)
  const int tid  = threadIdx.x;
  const int lane = tid & 63, wid = tid >> 6;
  const int wr = wid >> 1, wc = wid & 1;
  const int row0 = blockIdx.x * 128;
  const int fl = lane & 15, fh = lane >> 4;

  // ---- prefetch B(nt=0, kt=0) into regs (coalesced 16B/lane)
  short8 breg[4];
  #pragma unroll
  for (int j = 0; j < 4; ++j) {
    const int cidx = j * 256 + tid, brow = cidx >> 3, c = cidx & 7;
    breg[j] = *(const short8*)(wt + brow * 256 + c * 8);
  }

  // ---- stage A panel: 128x256 f32 -> bf16 in LDS (read once per block)
  #pragma unroll 4
  for (int j = 0; j < 16; ++j) {
    const int cidx = j * 256 + tid;            // 4096 chunks of 8 elems
    const int arow = cidx >> 5, c = cidx & 31;
    const int gr = min(row0 + arow, M - 1);
    const float* p = x + (size_t)gr * 256 + c * 8;
    const f32x4 lo = *(const f32x4*)p;
    const f32x4 hi = *(const f32x4*)(p + 4);
    short8 v;
    #pragma unroll
    for (int q = 0; q < 4; ++q) { v[q] = (short)f2bf(lo[q]); v[q + 4] = (short)f2bf(hi[q]); }
    *(short8*)(&lA[SWZA(arow, c)]) = v;
  }

  for (int nt = 0; nt < 8; ++nt) {
    f32x4 acc[4][4];
    #pragma unroll
    for (int i = 0; i < 4; ++i)
      #pragma unroll
      for (int j = 0; j < 4; ++j) acc[i][j] = (f32x4){0.f, 0.f, 0.f, 0.f};

    #pragma unroll
    for (int kt = 0; kt < 4; ++kt) {
      __syncthreads();                         // prev reads of lB done
      #pragma unroll
      for (int j = 0; j < 4; ++j) {            // regs -> lB
        const int cidx = j * 256 + tid, brow = cidx >> 3, c = cidx & 7;
        *(short8*)(&lB[SWZB(brow, c)]) = breg[j];
      }
      const int nt2 = (kt == 3) ? nt + 1 : nt; // prefetch next B chunk
      const int kt2 = (kt + 1) & 3;
      if (nt2 < 8) {
        const unsigned short* base = wt + nt2 * 32768 + kt2 * 64;
        #pragma unroll
        for (int j = 0; j < 4; ++j) {
          const int cidx = j * 256 + tid, brow = cidx >> 3, c = cidx & 7;
          breg[j] = *(const short8*)(base + brow * 256 + c * 8);
        }
      }
      __syncthreads();                         // lB ready

      short8 af[2][4], bq[2][4];
      #pragma unroll
      for (int kk = 0; kk < 2; ++kk) {
        #pragma unroll
        for (int fm = 0; fm < 4; ++fm)
          af[kk][fm] = *(const short8*)(&lA[SWZA(wr * 64 + fm * 16 + fl, kt * 8 + kk * 4 + fh)]);
        #pragma unroll
        for (int fn = 0; fn < 4; ++fn)
          bq[kk][fn] = *(const short8*)(&lB[SWZB(wc * 64 + fn * 16 + fl, kk * 4 + fh)]);
      }
      #pragma unroll
      for (int kk = 0; kk < 2; ++kk)
        #pragma unroll
        for (int fm = 0; fm < 4; ++fm)
          #pragma unroll
          for (int fn = 0; fn < 4; ++fn)
            acc[fm][fn] = __builtin_amdgcn_mfma_f32_16x16x32_bf16(af[kk][fm], bq[kk][fn], acc[fm][fn], 0, 0, 0);
    }

    // ---- epilogue for col-tile nt: 2 phases x 64 rows through lB scratch
    float bv[4];
    #pragma unroll
    for (int fn = 0; fn < 4; ++fn) {
      const int gcol = nt * 128 + wc * 64 + fn * 16 + fl;
      bv[fn] = (gcol < 256) ? b_int[gcol]
             : (gcol >= 512 && gcol < 768) ? b_tp[gcol - 512] : 0.0f;
    }
    #pragma unroll
    for (int p = 0; p < 2; ++p) {
      __syncthreads();                         // lB consumers done
      if (wr == p) {
        #pragma unroll
        for (int fm = 0; fm < 4; ++fm)
          #pragma unroll
          for (int fn = 0; fn < 4; ++fn) {
            const int col = wc * 64 + fn * 16 + fl;
            #pragma unroll
            for (int r = 0; r < 4; ++r) {
              const int lr = fm * 16 + fh * 4 + r;
              lB[SCR(lr, col >> 3) + (col & 7)] = f2bf(acc[fm][fn][r] + bv[fn]);
            }
          }
      }
      __syncthreads();
      const int tr = tid >> 2;
      const int grow = row0 + p * 64 + tr;
      if (grow < M) {
        #pragma unroll
        for (int j = 0; j < 4; ++j) {
          const int c = (tid & 3) + 4 * j;
          const short8 v = *(const short8*)(&lB[SCR(tr, c)]);
          *(short8*)(&Y[(size_t)grow * 1024 + nt * 128 + c * 8]) = v;
        }
      }
    }
  }
}

// ---- CSR build (both edge types in one launch)
#define HBLK 1954
__global__ void k_hist(const int* __restrict__ di, const int* __restrict__ dt,
                       int* __restrict__ ci, int* __restrict__ ct) {
  int b = blockIdx.x;
  const int* d; int* c;
  if (b < HBLK) { d = di; c = ci; } else { d = dt; c = ct; b -= HBLK; }
  int i = b * 256 + threadIdx.x;
  if (i < EE) atomicAdd(&c[d[i]], 1);
}

__global__ void k_scan(int* __restrict__ cnt_i, int* __restrict__ offs_i,
                       int* __restrict__ cnt_t, int* __restrict__ offs_t, int n) {
  int* cnt  = blockIdx.x ? cnt_t  : cnt_i;
  int* offs = blockIdx.x ? offs_t : offs_i;
  __shared__ int s_wsum[16];
  __shared__ int s_wpre[16];
  __shared__ int s_tot;
  const int tid = threadIdx.x;
  const int lane = tid & 63, wv = tid >> 6;
  int carry = 0;
  for (int base = 0; base < n; base += 1024) {
    const int i = base + tid;
    const int v = (i < n) ? cnt[i] : 0;
    int inc = v;
    #pragma unroll
    for (int d = 1; d < 64; d <<= 1) {
      int t = __shfl_up(inc, d, 64);
      if (lane >= d) inc += t;
    }
    if (lane == 63) s_wsum[wv] = inc;
    __syncthreads();
    if (tid == 0) {
      int s = 0;
      #pragma unroll
      for (int w2 = 0; w2 < 16; ++w2) { int t = s_wsum[w2]; s_wpre[w2] = s; s += t; }
      s_tot = s;
    }
    __syncthreads();
    const int excl = carry + s_wpre[wv] + inc - v;
    if (i < n) { offs[i] = excl; cnt[i] = excl; }
    carry += s_tot;
    __syncthreads();
  }
  if (tid == 0) offs[n] = carry;
}

__global__ void k_scatter(const int* __restrict__ ei, const int* __restrict__ et,
                          int* __restrict__ cur_i, int* __restrict__ cur_t,
                          int* __restrict__ so_i, int* __restrict__ so_t) {
  int b = blockIdx.x;
  const int* e; int* cur; int* so;
  if (b < HBLK) { e = ei; cur = cur_i; so = so_i; } else { e = et; cur = cur_t; so = so_t; b -= HBLK; }
  int i = b * 256 + threadIdx.x;
  if (i < EE) {
    int pos = atomicAdd(&cur[e[EE + i]], 1);
    so[pos] = e[i];
  }
}

// ---- fused aggregate: one wave per dst node; max(int) + sum(tp); single out write
__global__ void k_agg2(const unsigned short* __restrict__ Y,
                       const int* __restrict__ offs_i, const int* __restrict__ src_i,
                       const int* __restrict__ offs_t, const int* __restrict__ src_t,
                       float* __restrict__ out) {
  const int node = blockIdx.x * 4 + (threadIdx.x >> 6);
  if (node >= NN) return;
  const int lane = threadIdx.x & 63;
  const int c4 = lane << 2;
  const size_t rb = (size_t)node * 1024;

  const f32x4 ai = bf4(Y + rb + c4);         // A_int
  const f32x4 at = bf4(Y + rb + 512 + c4);   // A_tp
  f32x4 mx = (f32x4){0.f, 0.f, 0.f, 0.f};
  f32x4 sm = (f32x4){0.f, 0.f, 0.f, 0.f};

  {
    int e = offs_i[node];
    const int end = offs_i[node + 1];
    for (; e + 4 <= end; e += 4) {
      const int s0 = src_i[e], s1 = src_i[e + 1], s2 = src_i[e + 2], s3 = src_i[e + 3];
      const f32x4 b0 = bf4(Y + (size_t)s0 * 1024 + 256 + c4);
      const f32x4 b1 = bf4(Y + (size_t)s1 * 1024 + 256 + c4);
      const f32x4 b2 = bf4(Y + (size_t)s2 * 1024 + 256 + c4);
      const f32x4 b3 = bf4(Y + (size_t)s3 * 1024 + 256 + c4);
      #pragma unroll
      for (int j = 0; j < 4; ++j) {
        float m0 = fmaxf(fmaxf(ai[j] + b0[j], 0.0f), fmaxf(ai[j] + b1[j], 0.0f));
        float m1 = fmaxf(fmaxf(ai[j] + b2[j], 0.0f), fmaxf(ai[j] + b3[j], 0.0f));
        mx[j] = fmaxf(mx[j], fmaxf(m0, m1));
      }
    }
    for (; e < end; ++e) {
      const int s0 = src_i[e];
      const f32x4 b0 = bf4(Y + (size_t)s0 * 1024 + 256 + c4);
      #pragma unroll
      for (int j = 0; j < 4; ++j) mx[j] = fmaxf(mx[j], fmaxf(ai[j] + b0[j], 0.0f));
    }
  }
  {
    int e = offs_t[node];
    const int end = offs_t[node + 1];
    for (; e + 4 <= end; e += 4) {
      const int s0 = src_t[e], s1 = src_t[e + 1], s2 = src_t[e + 2], s3 = src_t[e + 3];
      const f32x4 b0 = bf4(Y + (size_t)s0 * 1024 + 768 + c4);
      const f32x4 b1 = bf4(Y + (size_t)s1 * 1024 + 768 + c4);
      const f32x4 b2 = bf4(Y + (size_t)s2 * 1024 + 768 + c4);
      const f32x4 b3 = bf4(Y + (size_t)s3 * 1024 + 768 + c4);
      #pragma unroll
      for (int j = 0; j < 4; ++j)
        sm[j] += (fmaxf(at[j] + b0[j], 0.0f) + fmaxf(at[j] + b1[j], 0.0f))
               + (fmaxf(at[j] + b2[j], 0.0f) + fmaxf(at[j] + b3[j], 0.0f));
    }
    for (; e < end; ++e) {
      const int s0 = src_t[e];
      const f32x4 b0 = bf4(Y + (size_t)s0 * 1024 + 768 + c4);
      #pragma unroll
      for (int j = 0; j < 4; ++j) sm[j] += fmaxf(at[j] + b0[j], 0.0f);
    }
  }

  f32x4 o;
  #pragma unroll
  for (int j = 0; j < 4; ++j) o[j] = mx[j] + sm[j];
  *(f32x4*)(out + (size_t)node * 256 + c4) = o;
}

extern "C" void kernel_launch(void* const* d_in, const int* in_sizes, int n_in,
                              void* d_out, int out_size, void* d_ws, size_t ws_size,
                              hipStream_t stream) {
  const float* x     = (const float*)d_in[0];
  const int*   e_tp  = (const int*)d_in[1];
  const int*   e_int = (const int*)d_in[2];
  const float* W_tp  = (const float*)d_in[3];
  const float* b_tp  = (const float*)d_in[4];
  const float* W_int = (const float*)d_in[5];
  const float* b_int = (const float*)d_in[6];
  float* out = (float*)d_out;

  char* w = (char*)d_ws;
  unsigned short* Y  = (unsigned short*)w;          // 102,400,000 B
  char* w2 = w + 102400000;                         // CSR region
  int* cnt_i  = (int*)(w2);                         // 200,000 (becomes cursor)
  int* cnt_t  = (int*)(w2 + 200000);                // 200,000
  int* offs_i = (int*)(w2 + 400000);                // 200,064
  int* offs_t = (int*)(w2 + 600064);                // 200,064
  int* ssrc_i = (int*)(w2 + 800128);                // 2,000,000
  int* ssrc_t = (int*)(w2 + 2800128);               // 2,000,000
  unsigned short* wt = (unsigned short*)(w2 + 4800128); // 524,288  -> peak ~107.7 MB

  k_prep<<<1024, 256, 0, stream>>>(W_int, W_tp, wt);
  k_gemm<<<dim3(391), dim3(256), 0, stream>>>(x, wt, b_int, b_tp, Y, NN);

  hipMemsetAsync(cnt_i, 0, 400000, stream);
  k_hist<<<2 * HBLK, 256, 0, stream>>>(e_int + EE, e_tp + EE, cnt_i, cnt_t);
  k_scan<<<2, 1024, 0, stream>>>(cnt_i, offs_i, cnt_t, offs_t, NN);
  k_scatter<<<2 * HBLK, 256, 0, stream>>>(e_int, e_tp, cnt_i, cnt_t, ssrc_i, ssrc_t);

  k_agg2<<<12500, 256, 0, stream>>>(Y, offs_i, ssrc_i, offs_t, ssrc_t, out);
}

// Round 5
// 287.708 us; speedup vs baseline: 1.6958x; 1.0088x over previous
//
#include <hip/hip_runtime.h>
#include <hip/hip_bf16.h>
#include <stdint.h>

#define NN 50000
#define EE 500000

typedef __attribute__((ext_vector_type(8))) short short8;
typedef __attribute__((ext_vector_type(4))) float f32x4;
typedef __attribute__((ext_vector_type(4))) unsigned short u16x4;

__device__ __forceinline__ unsigned short f2bf(float f) {
  union { float f; uint32_t u; } v; v.f = f;
  uint32_t u = v.u;
  return (unsigned short)((u + 0x7FFFu + ((u >> 16) & 1u)) >> 16);
}

__device__ __forceinline__ f32x4 bf4(const unsigned short* p) {
  u16x4 v = *(const u16x4*)p;
  f32x4 r;
  #pragma unroll
  for (int j = 0; j < 4; ++j) {
    union { uint32_t u; float f; } c; c.u = ((uint32_t)(unsigned short)v[j]) << 16; r[j] = c.f;
  }
  return r;
}

// ---- combined Wt [1024][256] bf16:
// rows   0..255  : W_int[:, :256] - W_int[:, 256:]   (A_int)
// rows 256..511  : W_int[:, 256:]                    (B_int)
// rows 512..767  : W_tp [:, :256] - W_tp [:, 256:]   (A_tp)
// rows 768..1023 : W_tp [:, 256:]                    (B_tp)
__global__ void k_prep(const float* __restrict__ Wi, const float* __restrict__ Wt,
                       unsigned short* __restrict__ wt) {
  int i = blockIdx.x * blockDim.x + threadIdx.x;
  if (i >= 1024 * 256) return;
  int o = i >> 8, k = i & 255;
  const float* W = (o < 512) ? Wi : Wt;
  int oo = o & 511;
  float v = (oo < 256) ? (W[oo * 512 + k] - W[oo * 512 + 256 + k])
                       : W[(oo - 256) * 512 + 256 + k];
  wt[i] = f2bf(v);
}

// LDS swizzles: chunk = 16B (8 bf16) unit; XOR low-3 chunk bits with row to
// spread the 8 16B bank-slots (2-way residual = free per m136).
#define SWZA(row, c) ((row) * 256 + ((((c) ^ ((row) & 7))) << 3))   // A: 32 chunks/row
#define SWZB(row, c) ((row) * 64  + ((((c) ^ ((row) & 7))) << 3))   // B: 8 chunks/row
#define SCR(row, c)  ((row) * 128 + ((((c) ^ ((row) & 7))) << 3))   // epi: 16 chunks/row

// ---- Y[M][1024](bf16) = x[M][256](f32) @ wt[1024][256]^T  (+bias on A cols)
// One block owns a 128-row A panel (whole panel in LDS, read from HBM once)
// and sweeps all 8 col-tiles of 128. BK=64, single B buffer + reg prefetch.
// LDS = 64K (A) + 16K (B/epilogue scratch) = 80 KB -> 2 blocks/CU.
__launch_bounds__(256, 2)
__global__ void k_gemm(const float* __restrict__ x, const unsigned short* __restrict__ wt,
                       const float* __restrict__ b_int, const float* __restrict__ b_tp,
                       unsigned short* __restrict__ Y, int M) {
  __shared__ unsigned short lA[128 * 256];   // 64 KB
  __shared__ unsigned short lB[128 * 64];    // 16 KB (B tile / epilogue scratch)
  const int tid  = threadIdx.x;
  const int lane = tid & 63, wid = tid >> 6;
  const int wr = wid >> 1, wc = wid & 1;
  const int row0 = blockIdx.x * 128;
  const int fl = lane & 15, fh = lane >> 4;

  // ---- prefetch B(nt=0, kt=0) into regs (coalesced 16B/lane)
  short8 breg[4];
  #pragma unroll
  for (int j = 0; j < 4; ++j) {
    const int cidx = j * 256 + tid, brow = cidx >> 3, c = cidx & 7;
    breg[j] = *(const short8*)(wt + brow * 256 + c * 8);
  }

  // ---- stage A panel: 128x256 f32 -> bf16 in LDS (read once per block)
  #pragma unroll 4
  for (int j = 0; j < 16; ++j) {
    const int cidx = j * 256 + tid;            // 4096 chunks of 8 elems
    const int arow = cidx >> 5, c = cidx & 31;
    const int gr = min(row0 + arow, M - 1);
    const float* p = x + (size_t)gr * 256 + c * 8;
    const f32x4 lo = *(const f32x4*)p;
    const f32x4 hi = *(const f32x4*)(p + 4);
    short8 v;
    #pragma unroll
    for (int q = 0; q < 4; ++q) { v[q] = (short)f2bf(lo[q]); v[q + 4] = (short)f2bf(hi[q]); }
    *(short8*)(&lA[SWZA(arow, c)]) = v;
  }

  for (int nt = 0; nt < 8; ++nt) {
    f32x4 acc[4][4];
    #pragma unroll
    for (int i = 0; i < 4; ++i)
      #pragma unroll
      for (int j = 0; j < 4; ++j) acc[i][j] = (f32x4){0.f, 0.f, 0.f, 0.f};

    #pragma unroll
    for (int kt = 0; kt < 4; ++kt) {
      __syncthreads();                         // prev reads of lB done
      #pragma unroll
      for (int j = 0; j < 4; ++j) {            // regs -> lB
        const int cidx = j * 256 + tid, brow = cidx >> 3, c = cidx & 7;
        *(short8*)(&lB[SWZB(brow, c)]) = breg[j];
      }
      const int nt2 = (kt == 3) ? nt + 1 : nt; // prefetch next B chunk
      const int kt2 = (kt + 1) & 3;
      if (nt2 < 8) {
        const unsigned short* base = wt + nt2 * 32768 + kt2 * 64;
        #pragma unroll
        for (int j = 0; j < 4; ++j) {
          const int cidx = j * 256 + tid, brow = cidx >> 3, c = cidx & 7;
          breg[j] = *(const short8*)(base + brow * 256 + c * 8);
        }
      }
      __syncthreads();                         // lB ready

      short8 af[2][4], bq[2][4];
      #pragma unroll
      for (int kk = 0; kk < 2; ++kk) {
        #pragma unroll
        for (int fm = 0; fm < 4; ++fm)
          af[kk][fm] = *(const short8*)(&lA[SWZA(wr * 64 + fm * 16 + fl, kt * 8 + kk * 4 + fh)]);
        #pragma unroll
        for (int fn = 0; fn < 4; ++fn)
          bq[kk][fn] = *(const short8*)(&lB[SWZB(wc * 64 + fn * 16 + fl, kk * 4 + fh)]);
      }
      #pragma unroll
      for (int kk = 0; kk < 2; ++kk)
        #pragma unroll
        for (int fm = 0; fm < 4; ++fm)
          #pragma unroll
          for (int fn = 0; fn < 4; ++fn)
            acc[fm][fn] = __builtin_amdgcn_mfma_f32_16x16x32_bf16(af[kk][fm], bq[kk][fn], acc[fm][fn], 0, 0, 0);
    }

    // ---- epilogue for col-tile nt: 2 phases x 64 rows through lB scratch
    float bv[4];
    #pragma unroll
    for (int fn = 0; fn < 4; ++fn) {
      const int gcol = nt * 128 + wc * 64 + fn * 16 + fl;
      bv[fn] = (gcol < 256) ? b_int[gcol]
             : (gcol >= 512 && gcol < 768) ? b_tp[gcol - 512] : 0.0f;
    }
    #pragma unroll
    for (int p = 0; p < 2; ++p) {
      __syncthreads();                         // lB consumers done
      if (wr == p) {
        #pragma unroll
        for (int fm = 0; fm < 4; ++fm)
          #pragma unroll
          for (int fn = 0; fn < 4; ++fn) {
            const int col = wc * 64 + fn * 16 + fl;
            #pragma unroll
            for (int r = 0; r < 4; ++r) {
              const int lr = fm * 16 + fh * 4 + r;
              lB[SCR(lr, col >> 3) + (col & 7)] = f2bf(acc[fm][fn][r] + bv[fn]);
            }
          }
      }
      __syncthreads();
      const int tr = tid >> 2;
      const int grow = row0 + p * 64 + tr;
      if (grow < M) {
        #pragma unroll
        for (int j = 0; j < 4; ++j) {
          const int c = (tid & 3) + 4 * j;
          const short8 v = *(const short8*)(&lB[SCR(tr, c)]);
          *(short8*)(&Y[(size_t)grow * 1024 + nt * 128 + c * 8]) = v;
        }
      }
    }
  }
}

// ---- CSR build (both edge types in one launch)
#define HBLK 1954
__global__ void k_hist(const int* __restrict__ di, const int* __restrict__ dt,
                       int* __restrict__ ci, int* __restrict__ ct) {
  int b = blockIdx.x;
  const int* d; int* c;
  if (b < HBLK) { d = di; c = ci; } else { d = dt; c = ct; b -= HBLK; }
  int i = b * 256 + threadIdx.x;
  if (i < EE) atomicAdd(&c[d[i]], 1);
}

__global__ void k_scan(int* __restrict__ cnt_i, int* __restrict__ offs_i,
                       int* __restrict__ cnt_t, int* __restrict__ offs_t, int n) {
  int* cnt  = blockIdx.x ? cnt_t  : cnt_i;
  int* offs = blockIdx.x ? offs_t : offs_i;
  __shared__ int s_wsum[16];
  __shared__ int s_wpre[16];
  __shared__ int s_tot;
  const int tid = threadIdx.x;
  const int lane = tid & 63, wv = tid >> 6;
  int carry = 0;
  for (int base = 0; base < n; base += 1024) {
    const int i = base + tid;
    const int v = (i < n) ? cnt[i] : 0;
    int inc = v;
    #pragma unroll
    for (int d = 1; d < 64; d <<= 1) {
      int t = __shfl_up(inc, d, 64);
      if (lane >= d) inc += t;
    }
    if (lane == 63) s_wsum[wv] = inc;
    __syncthreads();
    if (tid == 0) {
      int s = 0;
      #pragma unroll
      for (int w2 = 0; w2 < 16; ++w2) { int t = s_wsum[w2]; s_wpre[w2] = s; s += t; }
      s_tot = s;
    }
    __syncthreads();
    const int excl = carry + s_wpre[wv] + inc - v;
    if (i < n) { offs[i] = excl; cnt[i] = excl; }
    carry += s_tot;
    __syncthreads();
  }
  if (tid == 0) offs[n] = carry;
}

__global__ void k_scatter(const int* __restrict__ ei, const int* __restrict__ et,
                          int* __restrict__ cur_i, int* __restrict__ cur_t,
                          int* __restrict__ so_i, int* __restrict__ so_t) {
  int b = blockIdx.x;
  const int* e; int* cur; int* so;
  if (b < HBLK) { e = ei; cur = cur_i; so = so_i; } else { e = et; cur = cur_t; so = so_t; b -= HBLK; }
  int i = b * 256 + threadIdx.x;
  if (i < EE) {
    int pos = atomicAdd(&cur[e[EE + i]], 1);
    so[pos] = e[i];
  }
}

// ---- fused aggregate: one wave per dst node; max(int) + sum(tp); single out write
__global__ void k_agg2(const unsigned short* __restrict__ Y,
                       const int* __restrict__ offs_i, const int* __restrict__ src_i,
                       const int* __restrict__ offs_t, const int* __restrict__ src_t,
                       float* __restrict__ out) {
  const int node = blockIdx.x * 4 + (threadIdx.x >> 6);
  if (node >= NN) return;
  const int lane = threadIdx.x & 63;
  const int c4 = lane << 2;
  const size_t rb = (size_t)node * 1024;

  const f32x4 ai = bf4(Y + rb + c4);         // A_int
  const f32x4 at = bf4(Y + rb + 512 + c4);   // A_tp
  f32x4 mx = (f32x4){0.f, 0.f, 0.f, 0.f};
  f32x4 sm = (f32x4){0.f, 0.f, 0.f, 0.f};

  {
    int e = offs_i[node];
    const int end = offs_i[node + 1];
    for (; e + 4 <= end; e += 4) {
      const int s0 = src_i[e], s1 = src_i[e + 1], s2 = src_i[e + 2], s3 = src_i[e + 3];
      const f32x4 b0 = bf4(Y + (size_t)s0 * 1024 + 256 + c4);
      const f32x4 b1 = bf4(Y + (size_t)s1 * 1024 + 256 + c4);
      const f32x4 b2 = bf4(Y + (size_t)s2 * 1024 + 256 + c4);
      const f32x4 b3 = bf4(Y + (size_t)s3 * 1024 + 256 + c4);
      #pragma unroll
      for (int j = 0; j < 4; ++j) {
        float m0 = fmaxf(fmaxf(ai[j] + b0[j], 0.0f), fmaxf(ai[j] + b1[j], 0.0f));
        float m1 = fmaxf(fmaxf(ai[j] + b2[j], 0.0f), fmaxf(ai[j] + b3[j], 0.0f));
        mx[j] = fmaxf(mx[j], fmaxf(m0, m1));
      }
    }
    for (; e < end; ++e) {
      const int s0 = src_i[e];
      const f32x4 b0 = bf4(Y + (size_t)s0 * 1024 + 256 + c4);
      #pragma unroll
      for (int j = 0; j < 4; ++j) mx[j] = fmaxf(mx[j], fmaxf(ai[j] + b0[j], 0.0f));
    }
  }
  {
    int e = offs_t[node];
    const int end = offs_t[node + 1];
    for (; e + 4 <= end; e += 4) {
      const int s0 = src_t[e], s1 = src_t[e + 1], s2 = src_t[e + 2], s3 = src_t[e + 3];
      const f32x4 b0 = bf4(Y + (size_t)s0 * 1024 + 768 + c4);
      const f32x4 b1 = bf4(Y + (size_t)s1 * 1024 + 768 + c4);
      const f32x4 b2 = bf4(Y + (size_t)s2 * 1024 + 768 + c4);
      const f32x4 b3 = bf4(Y + (size_t)s3 * 1024 + 768 + c4);
      #pragma unroll
      for (int j = 0; j < 4; ++j)
        sm[j] += (fmaxf(at[j] + b0[j], 0.0f) + fmaxf(at[j] + b1[j], 0.0f))
               + (fmaxf(at[j] + b2[j], 0.0f) + fmaxf(at[j] + b3[j], 0.0f));
    }
    for (; e < end; ++e) {
      const int s0 = src_t[e];
      const f32x4 b0 = bf4(Y + (size_t)s0 * 1024 + 768 + c4);
      #pragma unroll
      for (int j = 0; j < 4; ++j) sm[j] += fmaxf(at[j] + b0[j], 0.0f);
    }
  }

  f32x4 o;
  #pragma unroll
  for (int j = 0; j < 4; ++j) o[j] = mx[j] + sm[j];
  *(f32x4*)(out + (size_t)node * 256 + c4) = o;
}

extern "C" void kernel_launch(void* const* d_in, const int* in_sizes, int n_in,
                              void* d_out, int out_size, void* d_ws, size_t ws_size,
                              hipStream_t stream) {
  const float* x     = (const float*)d_in[0];
  const int*   e_tp  = (const int*)d_in[1];
  const int*   e_int = (const int*)d_in[2];
  const float* W_tp  = (const float*)d_in[3];
  const float* b_tp  = (const float*)d_in[4];
  const float* W_int = (const float*)d_in[5];
  const float* b_int = (const float*)d_in[6];
  float* out = (float*)d_out;

  char* w = (char*)d_ws;
  unsigned short* Y  = (unsigned short*)w;          // 102,400,000 B
  char* w2 = w + 102400000;                         // CSR region
  int* cnt_i  = (int*)(w2);                         // 200,000 (becomes cursor)
  int* cnt_t  = (int*)(w2 + 200000);                // 200,000
  int* offs_i = (int*)(w2 + 400000);                // 200,064
  int* offs_t = (int*)(w2 + 600064);                // 200,064
  int* ssrc_i = (int*)(w2 + 800128);                // 2,000,000
  int* ssrc_t = (int*)(w2 + 2800128);               // 2,000,000
  unsigned short* wt = (unsigned short*)(w2 + 4800128); // 524,288  -> peak ~107.7 MB

  k_prep<<<1024, 256, 0, stream>>>(W_int, W_tp, wt);
  k_gemm<<<dim3(391), dim3(256), 0, stream>>>(x, wt, b_int, b_tp, Y, NN);

  hipMemsetAsync(cnt_i, 0, 400000, stream);
  k_hist<<<2 * HBLK, 256, 0, stream>>>(e_int + EE, e_tp + EE, cnt_i, cnt_t);
  k_scan<<<2, 1024, 0, stream>>>(cnt_i, offs_i, cnt_t, offs_t, NN);
  k_scatter<<<2 * HBLK, 256, 0, stream>>>(e_int, e_tp, cnt_i, cnt_t, ssrc_i, ssrc_t);

  k_agg2<<<12500, 256, 0, stream>>>(Y, offs_i, ssrc_i, offs_t, ssrc_t, out);
}